// Round 7
// baseline (145.217 us; speedup 1.0000x reference)
//
#include <hip/hip_runtime.h>
#include <hip/hip_bf16.h>

#define DDIM 448
#define NSTEP 14            // 448 / 32

typedef __hip_bfloat16 bf16;
typedef __attribute__((ext_vector_type(8))) short short8;   // 8 bf16 = 16B (MFMA A/B frag)
typedef __attribute__((ext_vector_type(4))) float f32x4;    // MFMA C/D frag / float4

__device__ __forceinline__ short bf_bits(float f) {
    bf16 h = __float2bfloat16(f);
    return *reinterpret_cast<short*>(&h);
}

// ---------------------------------------------------------------------------
// Kernel 1: fused weight  E[i][d] = Wq*diagA + Wk*diagB + Wv*diagC,
//           Wc[i][o] = sum_d E[i][d] * Wo[d][o].
// Output layout (verified): Wt[s][o][k] = Wc[s*32+k][o] — each lane's GEMM
// B-fragment is 16 contiguous bytes; a wave's fragment group is 1 KB linear.
// UNCHANGED.
// ---------------------------------------------------------------------------
__global__ __launch_bounds__(256) void prep_wc(
    const float* __restrict__ Wq, const float* __restrict__ Wk,
    const float* __restrict__ Wv, const float* __restrict__ Wo,
    const float* __restrict__ Ad, const float* __restrict__ Bd,
    const float* __restrict__ Cd, bf16* __restrict__ Wt)
{
    __shared__ __align__(16) bf16 As[64 * 32];
    __shared__ __align__(16) bf16 Bs[64 * 32];
    __shared__ float da[DDIM], db[DDIM], dc[DDIM];

    const int tid  = threadIdx.x;
    const int i0   = blockIdx.x * 64;
    const int o0   = blockIdx.y * 64;
    const int lane = tid & 63;
    const int wid  = tid >> 6;
    const int wm   = wid >> 1, wn = wid & 1;
    const int m_   = lane & 15, kq = lane >> 4;

    for (int d = tid; d < DDIM; d += 256) {
        da[d] = Ad[d * DDIM + d];
        db[d] = Bd[d * DDIM + d];
        dc[d] = Cd[d * DDIM + d];
    }

    const int dr  = tid >> 3;
    const int oc8 = (tid & 7) * 8;
    const int ir  = tid >> 2;
    const int dc8 = (tid & 3) * 8;

    f32x4 acc[2][2] = {};

    f32x4 w0 = *(const f32x4*)(Wo + dr * DDIM + o0 + oc8);
    f32x4 w1 = *(const f32x4*)(Wo + dr * DDIM + o0 + oc8 + 4);
    f32x4 q0 = *(const f32x4*)(Wq + (i0 + ir) * DDIM + dc8);
    f32x4 q1 = *(const f32x4*)(Wq + (i0 + ir) * DDIM + dc8 + 4);
    f32x4 t0 = *(const f32x4*)(Wk + (i0 + ir) * DDIM + dc8);
    f32x4 t1 = *(const f32x4*)(Wk + (i0 + ir) * DDIM + dc8 + 4);
    f32x4 v0 = *(const f32x4*)(Wv + (i0 + ir) * DDIM + dc8);
    f32x4 v1 = *(const f32x4*)(Wv + (i0 + ir) * DDIM + dc8 + 4);

    for (int k0 = 0; k0 < DDIM; k0 += 32) {
        __syncthreads();
        #pragma unroll
        for (int j = 0; j < 4; ++j) {
            As[(oc8 + j) * 32 + dr]     = __float2bfloat16(w0[j]);
            As[(oc8 + 4 + j) * 32 + dr] = __float2bfloat16(w1[j]);
        }
        short8 e;
        #pragma unroll
        for (int j = 0; j < 4; ++j) {
            e[j]     = bf_bits(q0[j] * da[k0 + dc8 + j]
                             + t0[j] * db[k0 + dc8 + j]
                             + v0[j] * dc[k0 + dc8 + j]);
            e[j + 4] = bf_bits(q1[j] * da[k0 + dc8 + 4 + j]
                             + t1[j] * db[k0 + dc8 + 4 + j]
                             + v1[j] * dc[k0 + dc8 + 4 + j]);
        }
        *(short8*)&Bs[ir * 32 + dc8] = e;
        __syncthreads();

        const int kn = (k0 + 32 < DDIM) ? k0 + 32 : 0;
        w0 = *(const f32x4*)(Wo + (kn + dr) * DDIM + o0 + oc8);
        w1 = *(const f32x4*)(Wo + (kn + dr) * DDIM + o0 + oc8 + 4);
        q0 = *(const f32x4*)(Wq + (i0 + ir) * DDIM + kn + dc8);
        q1 = *(const f32x4*)(Wq + (i0 + ir) * DDIM + kn + dc8 + 4);
        t0 = *(const f32x4*)(Wk + (i0 + ir) * DDIM + kn + dc8);
        t1 = *(const f32x4*)(Wk + (i0 + ir) * DDIM + kn + dc8 + 4);
        v0 = *(const f32x4*)(Wv + (i0 + ir) * DDIM + kn + dc8);
        v1 = *(const f32x4*)(Wv + (i0 + ir) * DDIM + kn + dc8 + 4);

        short8 af[2], bfr[2];
        #pragma unroll
        for (int mi = 0; mi < 2; ++mi)
            af[mi] = *(const short8*)&As[(wm * 32 + mi * 16 + m_) * 32 + kq * 8];
        #pragma unroll
        for (int ni = 0; ni < 2; ++ni)
            bfr[ni] = *(const short8*)&Bs[(wn * 32 + ni * 16 + m_) * 32 + kq * 8];
        #pragma unroll
        for (int mi = 0; mi < 2; ++mi)
            #pragma unroll
            for (int ni = 0; ni < 2; ++ni)
                acc[mi][ni] = __builtin_amdgcn_mfma_f32_16x16x32_bf16(
                    af[mi], bfr[ni], acc[mi][ni], 0, 0, 0);
    }

    #pragma unroll
    for (int mi = 0; mi < 2; ++mi)
        #pragma unroll
        for (int ni = 0; ni < 2; ++ni) {
            const int o = o0 + wm * 32 + mi * 16 + kq * 4;
            const int i = i0 + wn * 32 + ni * 16 + m_;
            bf16* dst = Wt + (i >> 5) * (DDIM * 32) + (i & 31);
            #pragma unroll
            for (int r = 0; r < 4; ++r)
                dst[(o + r) * 32] = __float2bfloat16(acc[mi][ni][r]);
        }
}

// ---------------------------------------------------------------------------
// Kernel 2: out[M x 448](fp32) = X(fp32) @ Wc.  B supplied as Wt[s][o][k].
// v7: B LIVES IN REGISTERS — no B-LDS, no global_load_lds, no vmcnt at any
// barrier. Rationale: Wt (392 KB) is L2-resident; each lane's fragment is
// 16 contiguous bytes and a wave's fragment group is a 1 KB coalesced
// global_load_dwordx4 burst. B frags are double-buffered in regs (bA/bB),
// loaded one step ahead; the compiler inserts precise per-register vmcnt
// waits (no hand-counted vmcnt — R2's failure mode is structurally gone).
// The per-step barrier now protects ONLY the 8 KB A-tile:
// s_waitcnt lgkmcnt(0) + raw s_barrier. All global traffic (X prefetch,
// B frags) flows freely across barriers. Main loop fully unrolled (2-step
// macro) so the bA/bB ping-pong is statically indexed (no scratch).
// Epilogue barriers are lgkm-only: v6's __syncthreads drained vmcnt(0),
// i.e. waited for 57 KB of store ACKs per stage; stores now retire in the
// background (s_endpgm guarantees final visibility).
// smem: A0 @0 (8K), A1 @8K (8K), Cb @16K (32 x 452 x 4B). Total 74240 B.
// VGPR: acc 112 + bA/bB 56 + af 16 + a-regs 8 + addr ~20 ≈ 212 ->
// __launch_bounds__(512,2): 8 waves/CU, 2/SIMD.
// ---------------------------------------------------------------------------
__global__ __launch_bounds__(512, 2) void gemm_xwc(
    const float* __restrict__ X, const bf16* __restrict__ Wt,
    float* __restrict__ out)
{
    __shared__ __align__(16) char smem[74240];

    const int tid  = threadIdx.x;
    const int lane = tid & 63;
    const int wid  = tid >> 6;               // 0..7
    const int wr   = wid >> 2;               // row half: rows wr*64 + [0,64)
    const int wc   = wid & 3;                // col quarter: cols wc*112 + [0,112)
    const int m_   = lane & 15;
    const int kq   = lane >> 4;
    const int row0 = blockIdx.x * 128;

    // A staging: 128x32 fp32 -> 8 f32/thread
    const int ar = tid >> 2;                 // 0..127
    const int ac = (tid & 3) * 8;            // 0,8,16,24
    const float* agp = X + (row0 + ar) * DDIM + ac;

    // B fragment base: lane (m_,kq) of frag ni at step s reads 16B from
    // Wt + s*14336 + (wc*112 + ni*16 + m_)*32 + kq*8   (1 KB/wave coalesced)
    const bf16* bgp = Wt + (wc * 112 + m_) * 32 + kq * 8;

    f32x4 acc[4][7] = {};
    short8 bA[7], bB[7];

    // ---- prologue: X(0) -> stage A(0); X(1) -> a-regs; B(0) -> bA
    f32x4 a0 = *(const f32x4*)(agp);
    f32x4 a1 = *(const f32x4*)(agp + 4);
    {
        bf16* A0 = (bf16*)smem;
        short8 w;
        #pragma unroll
        for (int j = 0; j < 4; ++j) {
            w[j] = bf_bits(a0[j]); w[j + 4] = bf_bits(a1[j]);
        }
        *(short8*)&A0[ar * 32 + ac] = w;     // byte addr = tid*16
    }
    a0 = *(const f32x4*)(agp + 32);          // X(1)
    a1 = *(const f32x4*)(agp + 36);
    #pragma unroll
    for (int j = 0; j < 7; ++j)
        bA[j] = *(const short8*)(bgp + j * 512);
    asm volatile("s_waitcnt lgkmcnt(0)" ::: "memory");
    __builtin_amdgcn_s_barrier();            // A(0) visible; B/X free-running

// One K-step. S is a compile-time literal after unroll; BCUR/BNXT are the
// named register arrays (static indexing only).
#define GSTEP(S, BCUR, BNXT)                                                 \
    {                                                                        \
        const bf16* Ac = (const bf16*)(smem + (((S) & 1) << 13));            \
        if ((S) + 1 < NSTEP) {                                               \
            const bf16* bs = bgp + ((S) + 1) * (DDIM * 32);                  \
            _Pragma("unroll")                                                \
            for (int j = 0; j < 7; ++j)                                      \
                BNXT[j] = *(const short8*)(bs + j * 512);                    \
            bf16* An = (bf16*)(smem + ((((S) + 1) & 1) << 13));              \
            short8 w;                                                        \
            _Pragma("unroll")                                                \
            for (int j = 0; j < 4; ++j) {                                    \
                w[j] = bf_bits(a0[j]); w[j + 4] = bf_bits(a1[j]);            \
            }                                                                \
            *(short8*)&An[ar * 32 + ac] = w;                                 \
        }                                                                    \
        if ((S) + 2 < NSTEP) {                                               \
            a0 = *(const f32x4*)(agp + ((S) + 2) * 32);                      \
            a1 = *(const f32x4*)(agp + ((S) + 2) * 32 + 4);                  \
        }                                                                    \
        short8 af[4];                                                        \
        _Pragma("unroll")                                                    \
        for (int mi = 0; mi < 4; ++mi)                                       \
            af[mi] = *(const short8*)&Ac[(wr * 64 + mi * 16 + m_) * 32       \
                                         + kq * 8];                          \
        _Pragma("unroll")                                                    \
        for (int mi = 0; mi < 4; ++mi)                                       \
            _Pragma("unroll")                                                \
            for (int ni = 0; ni < 7; ++ni)                                   \
                acc[mi][ni] = __builtin_amdgcn_mfma_f32_16x16x32_bf16(       \
                    af[mi], BCUR[ni], acc[mi][ni], 0, 0, 0);                 \
        asm volatile("s_waitcnt lgkmcnt(0)" ::: "memory");                   \
        __builtin_amdgcn_s_barrier();                                        \
    }

    #pragma unroll
    for (int ss = 0; ss < NSTEP; ss += 2) {
        GSTEP(ss,     bA, bB)
        GSTEP(ss + 1, bB, bA)
    }
#undef GSTEP

    // ---- epilogue: 4 stages of 32 rows; padded LDS bounce (stride 452 f32)
    // lgkm-only barriers: global stores are never drained in-kernel.
    float* Cb = (float*)(smem + 16384);       // 32 x 452 fp32
    #pragma unroll
    for (int t = 0; t < 4; ++t) {
        if (wr == (t >> 1)) {                 // wave-uniform: row-half owners
            #pragma unroll
            for (int mi2 = 0; mi2 < 2; ++mi2) {
                const int mi = (t & 1) * 2 + mi2;
                #pragma unroll
                for (int ni = 0; ni < 7; ++ni) {
                    const int col = wc * 112 + ni * 16 + m_;
                    #pragma unroll
                    for (int r = 0; r < 4; ++r)
                        Cb[(mi2 * 16 + kq * 4 + r) * 452 + col] = acc[mi][ni][r];
                }
            }
        }
        asm volatile("s_waitcnt lgkmcnt(0)" ::: "memory");
        __builtin_amdgcn_s_barrier();         // Cb writes visible
        // flat coalesced readout: 32x448 f32 = 3584 vec4 = 7 x 512
        const f32x4* Cb4 = (const f32x4*)Cb;
        f32x4* dst4 = (f32x4*)(out + (row0 + t * 32) * DDIM);
        #pragma unroll
        for (int j = 0; j < 7; ++j) {
            const int v   = j * 512 + tid;
            const int row = v / 112;          // 112 vec4 per output row
            const int cw  = v - row * 112;
            dst4[v] = Cb4[row * 113 + cw];    // 113 vec4 = 452 f32 stride
        }
        asm volatile("s_waitcnt lgkmcnt(0)" ::: "memory");
        __builtin_amdgcn_s_barrier();         // Cb reads done; safe to overwrite
    }
}

// ---------------------------------------------------------------------------
extern "C" void kernel_launch(void* const* d_in, const int* in_sizes, int n_in,
                              void* d_out, int out_size, void* d_ws, size_t ws_size,
                              hipStream_t stream) {
    const float* x  = (const float*)d_in[0];
    const float* Wq = (const float*)d_in[1];
    const float* Wk = (const float*)d_in[2];
    const float* Wv = (const float*)d_in[3];
    const float* Wo = (const float*)d_in[4];
    const float* Ad = (const float*)d_in[5];
    const float* Bd = (const float*)d_in[6];
    const float* Cd = (const float*)d_in[7];

    bf16*  Wt  = (bf16*)d_ws;                      // 448*448*2 = 392 KiB scratch
    float* out = (float*)d_out;

    const int M = in_sizes[0] / DDIM;              // 32768

    prep_wc<<<dim3(7, 7), 256, 0, stream>>>(Wq, Wk, Wv, Wo, Ad, Bd, Cd, Wt);
    gemm_xwc<<<M / 128, 512, 0, stream>>>(x, Wt, out);
}